// Round 2
// baseline (380.971 us; speedup 1.0000x reference)
//
#include <hip/hip_runtime.h>

#define BOX 71
#define NF 32
#define MAX_DIST_F 35.0f

// Full-occupancy zeroing: grid-stride float4 stores. rocclr's fillBufferAligned
// only reaches ~10% occupancy / ~1.55 TB/s; this saturates HBM write BW.
__global__ __launch_bounds__(256) void MakeGrid_zero_kernel(
    float4* __restrict__ out, size_t n4)
{
    size_t stride = (size_t)gridDim.x * blockDim.x;
    for (size_t i = (size_t)blockIdx.x * blockDim.x + threadIdx.x; i < n4; i += stride) {
        out[i] = make_float4(0.f, 0.f, 0.f, 0.f);
    }
}

// One 32-lane group per point: lane f handles feature f.
// features layout [B,N,F] -> consecutive lanes read consecutive floats (coalesced).
// atomicAdd target grid[0, x, y, z, f] -> 32 consecutive floats per point (coalesced burst).
__global__ __launch_bounds__(256) void MakeGrid_scatter_kernel(
    const float* __restrict__ coords,
    const float* __restrict__ features,
    float* __restrict__ grid,
    int total_points)
{
    int t = blockIdx.x * blockDim.x + threadIdx.x;
    int p = t >> 5;          // point index
    int f = t & 31;          // feature index
    if (p >= total_points) return;

    // All 32 lanes of the group load the same 3 coords (L1-cached broadcast).
    float cx = coords[p * 3 + 0];
    float cy = coords[p * 3 + 1];
    float cz = coords[p * 3 + 2];

    // jnp.round = round-half-to-even; rintf matches (default RNE rounding mode).
    // GRID_RES = 1.0 so (c + 35.0f) / 1.0f == c + 35.0f exactly.
    int gx = (int)rintf(cx + MAX_DIST_F);
    int gy = (int)rintf(cy + MAX_DIST_F);
    int gz = (int)rintf(cz + MAX_DIST_F);

    bool in_box = (gx >= 0) & (gx < BOX) &
                  (gy >= 0) & (gy < BOX) &
                  (gz >= 0) & (gz < BOX);
    if (!in_box) return;     // reference adds 0 at clamped index -> no-op

    float v = features[(size_t)p * NF + f];
    size_t idx = (((size_t)gx * BOX + gy) * BOX + gz) * NF + f;
    atomicAdd(grid + idx, v);  // device-scope by default on CDNA
}

extern "C" void kernel_launch(void* const* d_in, const int* in_sizes, int n_in,
                              void* d_out, int out_size, void* d_ws, size_t ws_size,
                              hipStream_t stream) {
    const float* coords   = (const float*)d_in[0];  // [B,N,3] fp32
    const float* features = (const float*)d_in[1];  // [B,N,F] fp32
    float* out = (float*)d_out;                     // [B,71,71,71,F] fp32

    // Zero all 366.5 MB at full BW (harness poisons d_out to 0xAA each call).
    // out_size = 91,625,216 floats, divisible by 4.
    size_t n4 = (size_t)out_size / 4;
    MakeGrid_zero_kernel<<<8192, 256, 0, stream>>>((float4*)out, n4);

    int total_points = in_sizes[0] / 3;             // B*N = 131072
    int total_threads = total_points * NF;
    int blocks = (total_threads + 255) / 256;
    MakeGrid_scatter_kernel<<<blocks, 256, 0, stream>>>(coords, features, out, total_points);
}